// Round 7
// baseline (3660.197 us; speedup 1.0000x reference)
//
#include <hip/hip_runtime.h>
#include <math.h>

// LSTMPredictor: B=2048 rows, 3x LSTMCell(H=50), P=17, T=512 + 32 future steps.
// fp32 buffers (runtime-sniffed, bf16 fallback kept). One block per CU owns M=8
// batch rows for the whole 544-step recurrence.
//
// R3: amdgpu_waves_per_eu attr is the working VGPR-budget lever (not
//     __launch_bounds__ at big blocks). R4/R5: VALU surgery ~null.
// R6 theory: LDS RETURN BANDWIDTH bound. A wave-uniform ds_read_b128 still
//     delivers 16B/lane = 1KB/wave to the RF (128B/clk). R5: 16 waves x 108
//     broadcast b128/step = ~14k clk LDS pipe per CU-step ~= the 16.2k step.
// R6 restructure: thread = (4 gates, K-tenth q): 500/512 threads, 8 waves,
//     waves_per_eu(2,2) -> 256-reg budget for 108 weight floats + 32 accs.
//     Reads per CU-step: 8 waves x 54 b128 (4x fewer instrs than R5).
//     gb stores: one float4 per row (4 adjacent gates). gb[q][m][gate].

#define BATCH    2048
#define PP       17
#define HH       50
#define GG       200      // 4*H
#define MROWS    8
#define NQ       10       // K split into tenths
#define NTHREADS 512
#define NACTIVE  500      // 50 gate-quads x 10 tenths
#define NBLOCKS  (BATCH / MROWS)   // 256
#define TQ1      7        // cell1 K=67 (x17 + h1 50) padded to 70 (w=0 rows)
#define TQ2      10       // cell2 K=100 exact
#define TQ3      10       // cell3 K=100 exact

__device__ __forceinline__ float bf2f(unsigned short u) {
    unsigned int i = ((unsigned int)u) << 16;
    float f; __builtin_memcpy(&f, &i, 4); return f;
}
__device__ __forceinline__ unsigned short f2bf(float f) {
    unsigned int i; __builtin_memcpy(&i, &f, 4);
    return (unsigned short)((i + 0x7fffu + ((i >> 16) & 1u)) >> 16);
}
__device__ __forceinline__ float ldin(const void* p, long i, bool f32) {
    return f32 ? ((const float*)p)[i] : bf2f(((const unsigned short*)p)[i]);
}
// saturation-safe fast sigmoid/tanh (v_exp_f32 + v_rcp_f32)
__device__ __forceinline__ float fsig(float x) {
    float t = exp2f(-1.44269504089f * x);          // +inf at x->-inf, 0 at x->+inf
    return __builtin_amdgcn_rcpf(1.0f + t);        // 0 / 1 at the limits
}
__device__ __forceinline__ float ftanh(float x) {
    float t = exp2f(2.88539008178f * x);           // e^(2x)
    return 1.0f - 2.0f * __builtin_amdgcn_rcpf(t + 1.0f);   // -1 / +1 at the limits
}

// fused mac pinned to arch VGPRs (identical numerics to fmaf)
#define FMAC(A, W, X) asm("v_fmac_f32 %0, %1, %2" : "+v"(A) : "v"(W), "v"(X))

// ---- dtype sniffer: bf16 weights decode to |v|<=0.142; fp32-as-bf16 gives junk ----
extern "C" __global__ void sniff_dtype(const unsigned short* __restrict__ w,
                                       int* __restrict__ flag) {
    int lane = threadIdx.x;
    bool bad = false;
#pragma unroll
    for (int t = 0; t < 4; ++t) {
        float v = bf2f(w[lane * 4 + t]);
        bad |= !(fabsf(v) <= 1.0f);
    }
    unsigned long long m = __ballot(bad);
    if (lane == 0) flag[0] = (m != 0ULL) ? 1 : 0;   // 1 => fp32 buffers
}

// gate phase: thread (g4, q) accumulates the K-tenth partial of gates
// 4*g4..4*g4+3 for all 8 rows. 2 b128 state reads per k feed 32 FMACs.
template <int TQ>
__device__ __forceinline__ void gate_phase(const float* __restrict__ S,
                                           float* __restrict__ gb,
                                           const float (&w)[4][TQ],
                                           int srow, int g4, int q, bool active) {
    if (active) {
        float a[4][8] = {};
        const float4* Sp = (const float4*)(S + (srow + q * TQ) * MROWS);
#pragma unroll
        for (int t = 0; t < TQ; ++t) {
            float4 lo = Sp[2 * t];         // rows m=0..3 of state k
            float4 hi = Sp[2 * t + 1];     // rows m=4..7
#pragma unroll
            for (int e = 0; e < 4; ++e) {
                float wv = w[e][t];
                FMAC(a[e][0], wv, lo.x); FMAC(a[e][1], wv, lo.y);
                FMAC(a[e][2], wv, lo.z); FMAC(a[e][3], wv, lo.w);
                FMAC(a[e][4], wv, hi.x); FMAC(a[e][5], wv, hi.y);
                FMAC(a[e][6], wv, hi.z); FMAC(a[e][7], wv, hi.w);
            }
        }
        // gb[q][m][gate]: 4 adjacent gates -> one float4 store per row
#pragma unroll
        for (int m = 0; m < 8; ++m) {
            float4 v; v.x = a[0][m]; v.y = a[1][m]; v.z = a[2][m]; v.w = a[3][m];
            *(float4*)(gb + (q * MROWS + m) * GG + 4 * g4) = v;
        }
    }
}

__device__ __forceinline__ void lstm_update(float* __restrict__ S,
                                            const float* __restrict__ gb,
                                            const float* __restrict__ bs,
                                            float& c, int hrow, int tid) {
    // caller guards tid < 400;  m = tid&7 (conflict-free h write), j = tid>>3
    int m = tid & 7;
    int j = tid >> 3;
    float ii = bs[j], ff = bs[50 + j], gg = bs[100 + j], oo = bs[150 + j];
#pragma unroll
    for (int q = 0; q < NQ; ++q) {
        // addr%32 = (8m+j)%32 across the wave -> 2-way (free)
        const float* b = gb + (q * MROWS + m) * GG;
        ii += b[j]; ff += b[50 + j]; gg += b[100 + j]; oo += b[150 + j];
    }
    float cn = fsig(ff) * c + fsig(ii) * ftanh(gg);
    c = cn;
    S[(hrow + j) * MROWS + m] = fsig(oo) * ftanh(cn);   // addr = hrow*8 + tid
}

extern "C" __global__
__attribute__((amdgpu_flat_work_group_size(NTHREADS, NTHREADS)))
__attribute__((amdgpu_waves_per_eu(2, 2)))
void lstm_persistent(const void* __restrict__ x,
                const void* __restrict__ wih1, const void* __restrict__ whh1,
                const void* __restrict__ bih1, const void* __restrict__ bhh1,
                const void* __restrict__ wih2, const void* __restrict__ whh2,
                const void* __restrict__ bih2, const void* __restrict__ bhh2,
                const void* __restrict__ wih3, const void* __restrict__ whh3,
                const void* __restrict__ bih3, const void* __restrict__ bhh3,
                const void* __restrict__ wlin, const void* __restrict__ blin,
                void* __restrict__ out, const int* __restrict__ flag,
                int T, int steps)
{
    const int tid = threadIdx.x;
    __shared__ float S[167 * MROWS];        // 0..16 x | 17..66 h1 | 67..116 h2 | 117..166 h3
    __shared__ float gb[NQ * MROWS * GG];   // [tenth][m][gate]  (64 KB)
    __shared__ float WLt[50 * PP];          // W_lin^T
    __shared__ float bs1[GG], bs2[GG], bs3[GG], bl[PP];

    const bool f32 = (flag[0] != 0);

    const int q  = tid / 50;                // K-tenth (<=2 distinct q per wave)
    const int g4 = tid - q * 50;            // gate-quad 0..49
    const bool active = (tid < NACTIVE);    // 500 of 512

    // ---- per-thread register weights (fp32, full precision): 108 floats ----
    float w1[4][TQ1], w2[4][TQ2], w3[4][TQ3];
    if (active) {
#pragma unroll
        for (int e = 0; e < 4; ++e) {
            const int g = 4 * g4 + e;
#pragma unroll
            for (int t = 0; t < TQ1; ++t) {          // cell1 K=67 (rows 67..69 zero)
                int k = q * TQ1 + t;
                w1[e][t] = (k < 17) ? ldin(wih1, (long)g * 17 + k, f32)
                         : (k < 67) ? ldin(whh1, (long)g * 50 + (k - 17), f32)
                                    : 0.0f;
            }
#pragma unroll
            for (int t = 0; t < TQ2; ++t) {          // cell2 K=100
                int k = q * TQ2 + t;
                w2[e][t] = (k < 50) ? ldin(wih2, (long)g * 50 + k, f32)
                                    : ldin(whh2, (long)g * 50 + (k - 50), f32);
            }
#pragma unroll
            for (int t = 0; t < TQ3; ++t) {          // cell3 K=100
                int k = q * TQ3 + t;
                w3[e][t] = (k < 50) ? ldin(wih3, (long)g * 50 + k, f32)
                                    : ldin(whh3, (long)g * 50 + (k - 50), f32);
            }
        }
    }

    // ---- stage biases, W_lin^T, zero h-state, preload x(step 0) ----
    if (tid < GG) {
        bs1[tid] = ldin(bih1, tid, f32) + ldin(bhh1, tid, f32);
        bs2[tid] = ldin(bih2, tid, f32) + ldin(bhh2, tid, f32);
        bs3[tid] = ldin(bih3, tid, f32) + ldin(bhh3, tid, f32);
    } else if (tid < GG + PP) {
        bl[tid - GG] = ldin(blin, tid - GG, f32);
    }
    for (int i = tid; i < 50 * PP; i += NTHREADS) {
        int k = i / PP, p = i - k * PP;
        WLt[i] = ldin(wlin, (long)p * 50 + k, f32);
    }
    for (int i = tid; i < 1200; i += NTHREADS) S[136 + i] = 0.0f;   // h1,h2,h3 = 0

    const long rowBase = (long)blockIdx.x * MROWS;
    const long xStride = (long)T * PP;
    if (tid < 136) {
        int m = tid / PP, p = tid - (tid / PP) * PP;
        S[p * MROWS + m] = ldin(x, (rowBase + m) * xStride + p, f32);
    }
    float c1 = 0.0f, c2 = 0.0f, c3 = 0.0f;
    __syncthreads();

    const long outStride = (long)steps * PP;
    for (int s = 0; s < steps; ++s) {
        gate_phase<TQ1>(S, gb, w1, 0, g4, q, active);           // cell1: [x|h1]
        __syncthreads();
        if (tid < 400) lstm_update(S, gb, bs1, c1, 17, tid);    // write h1
        __syncthreads();
        gate_phase<TQ2>(S, gb, w2, 17, g4, q, active);          // cell2: [h1|h2]
        __syncthreads();
        if (tid < 400) lstm_update(S, gb, bs2, c2, 67, tid);    // write h2
        __syncthreads();
        gate_phase<TQ3>(S, gb, w3, 67, g4, q, active);          // cell3: [h2|h3]
        __syncthreads();
        if (tid < 400) lstm_update(S, gb, bs3, c3, 117, tid);   // write h3
        __syncthreads();
        // ---- linear head + output + next input (feedback or global x) ----
        if (tid < 136) {
            int m = tid / PP, p = tid - (tid / PP) * PP;
            float acc = bl[p];
#pragma unroll
            for (int k = 0; k < 50; ++k)
                acc = fmaf(WLt[k * PP + p], S[(117 + k) * MROWS + m], acc);
            long oi = (rowBase + m) * outStride + (long)s * PP + p;
            if (f32) ((float*)out)[oi] = acc;
            else     ((unsigned short*)out)[oi] = f2bf(acc);
            if (s + 1 >= T && s + 1 < steps)                    // autoregressive feedback
                S[p * MROWS + m] = acc;
        } else if (tid >= 256 && tid < 392) {
            int u = tid - 256;
            int m = u / PP, p = u - (u / PP) * PP;
            if (s + 1 < T)                                      // prefetch next x chunk
                S[p * MROWS + m] = ldin(x, (rowBase + m) * xStride + (long)(s + 1) * PP + p, f32);
        }
        __syncthreads();
    }
}

extern "C" void kernel_launch(void* const* d_in, const int* in_sizes, int n_in,
                              void* d_out, int out_size, void* d_ws, size_t ws_size,
                              hipStream_t stream) {
    (void)ws_size; (void)n_in;
    int* flag = (int*)d_ws;

    const int T     = in_sizes[0] / (BATCH * PP);   // 512
    const int steps = out_size / (BATCH * PP);      // 544

    sniff_dtype<<<1, 64, 0, stream>>>((const unsigned short*)d_in[1], flag);

    lstm_persistent<<<NBLOCKS, NTHREADS, 0, stream>>>(
        d_in[0],
        d_in[1], d_in[2], d_in[3], d_in[4],
        d_in[5], d_in[6], d_in[7], d_in[8],
        d_in[9], d_in[10], d_in[11], d_in[12],
        d_in[13], d_in[14],
        d_out, flag, T, steps);
}

// Round 8
// 3163.536 us; speedup vs baseline: 1.1570x; 1.1570x over previous
//
#include <hip/hip_runtime.h>
#include <math.h>

// LSTMPredictor: B=2048 rows, 3x LSTMCell(H=50), P=17, T=512 + 32 future steps.
// fp32 buffers (runtime-sniffed, bf16 fallback kept). One block per CU owns M=8
// batch rows for the whole 544-step recurrence.
//
// Evidence ledger:
//   R0 (512thr, __launch_bounds__(512,2), VGPR=128): VALU inflation 1.4x.
//   R5/R6 (amdgpu_waves_per_eu attr, VGPR=56/100):   VALU inflation 2.6x --
//     accumulators homed in AGPRs (read+fma+write per MAC). Structure knobs
//     (read traffic 4x down in R6) moved NOTHING: not LDS-BW bound, not
//     read-count bound. The multiplicative lever is allocation health.
// R7: R6 structure (4 gates x K-tenth, 500/512 active, gb[q][m][gate]) with
//     R0's PROVEN qualifier __launch_bounds__(512,2) and plain fmaf (no asm).
//     Single-variable test: VGPR_Count must jump ~100 -> ~128+ and busy
//     cyc/step drop ~2x. Else allocator policy follows block size -> R8
//     pivots to 2-blocks/CU.

#define BATCH    2048
#define PP       17
#define HH       50
#define GG       200      // 4*H
#define MROWS    8
#define NQ       10       // K split into tenths
#define NTHREADS 512
#define NACTIVE  500      // 50 gate-quads x 10 tenths
#define NBLOCKS  (BATCH / MROWS)   // 256
#define TQ1      7        // cell1 K=67 (x17 + h1 50) padded to 70 (w=0 rows)
#define TQ2      10       // cell2 K=100 exact
#define TQ3      10       // cell3 K=100 exact

__device__ __forceinline__ float bf2f(unsigned short u) {
    unsigned int i = ((unsigned int)u) << 16;
    float f; __builtin_memcpy(&f, &i, 4); return f;
}
__device__ __forceinline__ unsigned short f2bf(float f) {
    unsigned int i; __builtin_memcpy(&i, &f, 4);
    return (unsigned short)((i + 0x7fffu + ((i >> 16) & 1u)) >> 16);
}
__device__ __forceinline__ float ldin(const void* p, long i, bool f32) {
    return f32 ? ((const float*)p)[i] : bf2f(((const unsigned short*)p)[i]);
}
// saturation-safe fast sigmoid/tanh (v_exp_f32 + v_rcp_f32)
__device__ __forceinline__ float fsig(float x) {
    float t = exp2f(-1.44269504089f * x);          // +inf at x->-inf, 0 at x->+inf
    return __builtin_amdgcn_rcpf(1.0f + t);        // 0 / 1 at the limits
}
__device__ __forceinline__ float ftanh(float x) {
    float t = exp2f(2.88539008178f * x);           // e^(2x)
    return 1.0f - 2.0f * __builtin_amdgcn_rcpf(t + 1.0f);   // -1 / +1 at the limits
}

// ---- dtype sniffer: bf16 weights decode to |v|<=0.142; fp32-as-bf16 gives junk ----
extern "C" __global__ void sniff_dtype(const unsigned short* __restrict__ w,
                                       int* __restrict__ flag) {
    int lane = threadIdx.x;
    bool bad = false;
#pragma unroll
    for (int t = 0; t < 4; ++t) {
        float v = bf2f(w[lane * 4 + t]);
        bad |= !(fabsf(v) <= 1.0f);
    }
    unsigned long long m = __ballot(bad);
    if (lane == 0) flag[0] = (m != 0ULL) ? 1 : 0;   // 1 => fp32 buffers
}

// gate phase: thread (g4, q) accumulates the K-tenth partial of gates
// 4*g4..4*g4+3 for all 8 rows. 2 b128 state reads per k feed 32 fmafs.
template <int TQ>
__device__ __forceinline__ void gate_phase(const float* __restrict__ S,
                                           float* __restrict__ gb,
                                           const float (&w)[4][TQ],
                                           int srow, int g4, int q, bool active) {
    if (active) {
        float a[4][8] = {};
        const float4* Sp = (const float4*)(S + (srow + q * TQ) * MROWS);
#pragma unroll
        for (int t = 0; t < TQ; ++t) {
            float4 lo = Sp[2 * t];         // rows m=0..3 of state k
            float4 hi = Sp[2 * t + 1];     // rows m=4..7
#pragma unroll
            for (int e = 0; e < 4; ++e) {
                float wv = w[e][t];
                a[e][0] = fmaf(wv, lo.x, a[e][0]); a[e][1] = fmaf(wv, lo.y, a[e][1]);
                a[e][2] = fmaf(wv, lo.z, a[e][2]); a[e][3] = fmaf(wv, lo.w, a[e][3]);
                a[e][4] = fmaf(wv, hi.x, a[e][4]); a[e][5] = fmaf(wv, hi.y, a[e][5]);
                a[e][6] = fmaf(wv, hi.z, a[e][6]); a[e][7] = fmaf(wv, hi.w, a[e][7]);
            }
        }
        // gb[q][m][gate]: 4 adjacent gates -> one float4 store per row
#pragma unroll
        for (int m = 0; m < 8; ++m) {
            float4 v; v.x = a[0][m]; v.y = a[1][m]; v.z = a[2][m]; v.w = a[3][m];
            *(float4*)(gb + (q * MROWS + m) * GG + 4 * g4) = v;
        }
    }
}

__device__ __forceinline__ void lstm_update(float* __restrict__ S,
                                            const float* __restrict__ gb,
                                            const float* __restrict__ bs,
                                            float& c, int hrow, int tid) {
    // caller guards tid < 400;  m = tid&7 (conflict-free h write), j = tid>>3
    int m = tid & 7;
    int j = tid >> 3;
    float ii = bs[j], ff = bs[50 + j], gg = bs[100 + j], oo = bs[150 + j];
#pragma unroll
    for (int q = 0; q < NQ; ++q) {
        // addr%32 = (8m+j)%32 across the wave -> 2-way (free)
        const float* b = gb + (q * MROWS + m) * GG;
        ii += b[j]; ff += b[50 + j]; gg += b[100 + j]; oo += b[150 + j];
    }
    float cn = fsig(ff) * c + fsig(ii) * ftanh(gg);
    c = cn;
    S[(hrow + j) * MROWS + m] = fsig(oo) * ftanh(cn);   // addr = hrow*8 + tid
}

extern "C" __global__ void __launch_bounds__(NTHREADS, 2)
lstm_persistent(const void* __restrict__ x,
                const void* __restrict__ wih1, const void* __restrict__ whh1,
                const void* __restrict__ bih1, const void* __restrict__ bhh1,
                const void* __restrict__ wih2, const void* __restrict__ whh2,
                const void* __restrict__ bih2, const void* __restrict__ bhh2,
                const void* __restrict__ wih3, const void* __restrict__ whh3,
                const void* __restrict__ bih3, const void* __restrict__ bhh3,
                const void* __restrict__ wlin, const void* __restrict__ blin,
                void* __restrict__ out, const int* __restrict__ flag,
                int T, int steps)
{
    const int tid = threadIdx.x;
    __shared__ float S[167 * MROWS];        // 0..16 x | 17..66 h1 | 67..116 h2 | 117..166 h3
    __shared__ float gb[NQ * MROWS * GG];   // [tenth][m][gate]  (64 KB)
    __shared__ float WLt[50 * PP];          // W_lin^T
    __shared__ float bs1[GG], bs2[GG], bs3[GG], bl[PP];

    const bool f32 = (flag[0] != 0);

    const int q  = tid / 50;                // K-tenth (<=2 distinct q per wave)
    const int g4 = tid - q * 50;            // gate-quad 0..49
    const bool active = (tid < NACTIVE);    // 500 of 512

    // ---- per-thread register weights (fp32, full precision): 108 floats ----
    float w1[4][TQ1], w2[4][TQ2], w3[4][TQ3];
    if (active) {
#pragma unroll
        for (int e = 0; e < 4; ++e) {
            const int g = 4 * g4 + e;
#pragma unroll
            for (int t = 0; t < TQ1; ++t) {          // cell1 K=67 (rows 67..69 zero)
                int k = q * TQ1 + t;
                w1[e][t] = (k < 17) ? ldin(wih1, (long)g * 17 + k, f32)
                         : (k < 67) ? ldin(whh1, (long)g * 50 + (k - 17), f32)
                                    : 0.0f;
            }
#pragma unroll
            for (int t = 0; t < TQ2; ++t) {          // cell2 K=100
                int k = q * TQ2 + t;
                w2[e][t] = (k < 50) ? ldin(wih2, (long)g * 50 + k, f32)
                                    : ldin(whh2, (long)g * 50 + (k - 50), f32);
            }
#pragma unroll
            for (int t = 0; t < TQ3; ++t) {          // cell3 K=100
                int k = q * TQ3 + t;
                w3[e][t] = (k < 50) ? ldin(wih3, (long)g * 50 + k, f32)
                                    : ldin(whh3, (long)g * 50 + (k - 50), f32);
            }
        }
    }

    // ---- stage biases, W_lin^T, zero h-state, preload x(step 0) ----
    if (tid < GG) {
        bs1[tid] = ldin(bih1, tid, f32) + ldin(bhh1, tid, f32);
        bs2[tid] = ldin(bih2, tid, f32) + ldin(bhh2, tid, f32);
        bs3[tid] = ldin(bih3, tid, f32) + ldin(bhh3, tid, f32);
    } else if (tid < GG + PP) {
        bl[tid - GG] = ldin(blin, tid - GG, f32);
    }
    for (int i = tid; i < 50 * PP; i += NTHREADS) {
        int k = i / PP, p = i - k * PP;
        WLt[i] = ldin(wlin, (long)p * 50 + k, f32);
    }
    for (int i = tid; i < 1200; i += NTHREADS) S[136 + i] = 0.0f;   // h1,h2,h3 = 0

    const long rowBase = (long)blockIdx.x * MROWS;
    const long xStride = (long)T * PP;
    if (tid < 136) {
        int m = tid / PP, p = tid - (tid / PP) * PP;
        S[p * MROWS + m] = ldin(x, (rowBase + m) * xStride + p, f32);
    }
    float c1 = 0.0f, c2 = 0.0f, c3 = 0.0f;
    __syncthreads();

    const long outStride = (long)steps * PP;
    for (int s = 0; s < steps; ++s) {
        gate_phase<TQ1>(S, gb, w1, 0, g4, q, active);           // cell1: [x|h1]
        __syncthreads();
        if (tid < 400) lstm_update(S, gb, bs1, c1, 17, tid);    // write h1
        __syncthreads();
        gate_phase<TQ2>(S, gb, w2, 17, g4, q, active);          // cell2: [h1|h2]
        __syncthreads();
        if (tid < 400) lstm_update(S, gb, bs2, c2, 67, tid);    // write h2
        __syncthreads();
        gate_phase<TQ3>(S, gb, w3, 67, g4, q, active);          // cell3: [h2|h3]
        __syncthreads();
        if (tid < 400) lstm_update(S, gb, bs3, c3, 117, tid);   // write h3
        __syncthreads();
        // ---- linear head + output + next input (feedback or global x) ----
        if (tid < 136) {
            int m = tid / PP, p = tid - (tid / PP) * PP;
            float acc = bl[p];
#pragma unroll
            for (int k = 0; k < 50; ++k)
                acc = fmaf(WLt[k * PP + p], S[(117 + k) * MROWS + m], acc);
            long oi = (rowBase + m) * outStride + (long)s * PP + p;
            if (f32) ((float*)out)[oi] = acc;
            else     ((unsigned short*)out)[oi] = f2bf(acc);
            if (s + 1 >= T && s + 1 < steps)                    // autoregressive feedback
                S[p * MROWS + m] = acc;
        } else if (tid >= 256 && tid < 392) {
            int u = tid - 256;
            int m = u / PP, p = u - (u / PP) * PP;
            if (s + 1 < T)                                      // prefetch next x chunk
                S[p * MROWS + m] = ldin(x, (rowBase + m) * xStride + (long)(s + 1) * PP + p, f32);
        }
        __syncthreads();
    }
}

extern "C" void kernel_launch(void* const* d_in, const int* in_sizes, int n_in,
                              void* d_out, int out_size, void* d_ws, size_t ws_size,
                              hipStream_t stream) {
    (void)ws_size; (void)n_in;
    int* flag = (int*)d_ws;

    const int T     = in_sizes[0] / (BATCH * PP);   // 512
    const int steps = out_size / (BATCH * PP);      // 544

    sniff_dtype<<<1, 64, 0, stream>>>((const unsigned short*)d_in[1], flag);

    lstm_persistent<<<NBLOCKS, NTHREADS, 0, stream>>>(
        d_in[0],
        d_in[1], d_in[2], d_in[3], d_in[4],
        d_in[5], d_in[6], d_in[7], d_in[8],
        d_in[9], d_in[10], d_in[11], d_in[12],
        d_in[13], d_in[14],
        d_out, flag, T, steps);
}